// Round 7
// baseline (252.659 us; speedup 1.0000x reference)
//
#include <hip/hip_runtime.h>
#include <cstdint>
#include <cstddef>

// B=2, N=4096, QDIM=768, H=8, D=64, INNER=512
// Pipeline: cvt x->bf16; LDS-tiled weight transposes; QKV gemm (bf16 MFMA)
// writing q[b,h,n,d] (pre-scaled by 0.125*log2e) and K/V in MFMA-FRAGMENT-
// TILED layouts (R12: producer writes fragment order so attention's loads
// are wave-contiguous 1KB reads); flash attention (R13: 64-q blocks, grid
// 1024 = 4 blocks/CU -> 16 waves/CU; R12 was occupancy-capped at 8 waves/CU
// with VALUBusy 53% / VGPR 124 -- the VALU pipe idled on dep chains):
// 32x32x16 MFMA, swapped QK^T, register-resident P (cvt_pk_bf16 + verified
// shfl_xor(32) exchange), direct coalesced global loads, no LDS in main
// loop; XCD-swizzled bh (2 bh = 2MB per XCD, L2-resident); VALU row-sums;
// out gemm + bias (C^T, float4 stores) -> fp32.

typedef __attribute__((ext_vector_type(8))) short short8;
typedef __attribute__((ext_vector_type(4))) float f32x4;
typedef __attribute__((ext_vector_type(16))) float f32x16;
typedef __attribute__((ext_vector_type(4))) unsigned int uint4v;

__device__ __forceinline__ unsigned short f2bf(float f) {
  // round-to-nearest-even bf16 (truncation's systematic -2^-9 bias through
  // 3 GEMM stages would blow the threshold)
  unsigned int u = __float_as_uint(f);
  u = (u + 0x7fffu + ((u >> 16) & 1u)) >> 16;
  return (unsigned short)u;
}

__device__ __forceinline__ float fast_exp2(float x) {
#if __has_builtin(__builtin_amdgcn_exp2f)
  return __builtin_amdgcn_exp2f(x);  // raw v_exp_f32
#else
  return __expf(x * 0.69314718055994531f);  // e^(x ln2) = 2^x
#endif
}

__device__ __forceinline__ void gld16(const void* g, void* l) {
  // async global->LDS, 16B/lane; LDS dest = wave-uniform base + lane*16
  __builtin_amdgcn_global_load_lds(
      (__attribute__((address_space(1))) void*)const_cast<void*>(g),
      (__attribute__((address_space(3))) void*)l, 16, 0, 0);
}

__device__ __forceinline__ unsigned int cvtpk_bf16(float lo, float hi) {
  // {lo16 = bf16_rne(lo), hi16 = bf16_rne(hi)} — single VALU op.
  // HW-verified in R11/R12 (passed, absmax matches bit-op RNE path).
  unsigned int r;
  asm("v_cvt_pk_bf16_f32 %0, %1, %2" : "=v"(r) : "v"(lo), "v"(hi));
  return r;
}

// ---------------- prep kernels ----------------

__global__ __launch_bounds__(256) void cvt_x_k(const float* __restrict__ x,
                                               unsigned short* __restrict__ xb) {
  const size_t i = ((size_t)blockIdx.x * 256 + threadIdx.x) * 4;  // 6291456 elems
  const float4 v = *(const float4*)(x + i);
  ushort4 u;
  u.x = f2bf(v.x); u.y = f2bf(v.y); u.z = f2bf(v.z); u.w = f2bf(v.w);
  *(ushort4*)(xb + i) = u;
}

// One LDS-tiled transpose for all 4 weight matrices. fp32 [R][C] -> bf16 [C][R].
__global__ __launch_bounds__(256) void transpose_w_k(
    const float* __restrict__ Wq, const float* __restrict__ Wk,
    const float* __restrict__ Wv, const float* __restrict__ Wout,
    unsigned short* __restrict__ Wt,   // [3][512][768]
    unsigned short* __restrict__ WoT)  // [768][512]
{
  __shared__ float t[32][33];  // +1 pad: conflict-free transpose
  const int z = blockIdx.z;    // 0..2: Wq/Wk/Wv (768x512); 3: Wout (512x768)
  const float* src = (z == 0) ? Wq : (z == 1) ? Wk : (z == 2) ? Wv : Wout;
  const int R = (z < 3) ? 768 : 512, C = (z < 3) ? 512 : 768;
  unsigned short* dst = (z < 3) ? (Wt + (size_t)z * 393216) : WoT;
  const int tx = threadIdx.x & 31, ty = threadIdx.x >> 5;  // 32 x 8
  const int c0 = blockIdx.x * 32, r0 = blockIdx.y * 32;
  if (c0 >= C || r0 >= R) return;
#pragma unroll
  for (int k = 0; k < 4; ++k)
    t[ty + 8 * k][tx] = src[(size_t)(r0 + ty + 8 * k) * C + c0 + tx];
  __syncthreads();
#pragma unroll
  for (int k = 0; k < 4; ++k)
    dst[(size_t)(c0 + ty + 8 * k) * R + r0 + tx] = f2bf(t[tx][ty + 8 * k]);
}

// ---------------- QKV projection GEMM ----------------
// C[8192][512] = xb[8192][768] @ Wt[z]^T ; packed-store epilogues:
// z=0 (q, layout [bh][nseq][d]): SWAPPED mfma -> C^T, lane's 4 r-values are
//   4 consecutive d at fixed nseq -> one ushort4; pre-scaled 0.125*log2(e).
// z=1 (k, FRAGMENT-TILED [bh][kti][c][lane][8], kti=32-key tile,
//   lane=hi*32+l31): lane's 4 r-values are d0..d0+3 at fixed key; c=d>>4,
//   hi=(d>>3)&1, l31=key&31, e0=d0&7 in {0,4} -> one 8B-aligned ushort4.
// z=2 (v, FRAGMENT-TILED [bh][kti][dt][kc][lane][8], lane=hi*32+(d&31)):
//   NORMAL mfma, lane's 4 r-values are key0..key0+3 at fixed d; kc=
//   (key>>4)&1, hi=(key>>3)&1, dt=(d>>5)&1, e0=key0&7 -> one ushort4.
// These layouts make every attention K/V fragment load a wave-contiguous
// 1KB global read (lane-linear): R12 took attn 142 -> 88us with them.

__global__ __launch_bounds__(256) void gemm_qkv_k(
    const unsigned short* __restrict__ A,    // xb [8192][768]
    const unsigned short* __restrict__ Wt,   // [3][512][768]
    unsigned short* __restrict__ qb, unsigned short* __restrict__ kb,
    unsigned short* __restrict__ vtb) {
  __shared__ __align__(16) short Al[4096];  // [128][32]
  __shared__ __align__(16) short Bl[4096];  // [128][32]
  const int tid = threadIdx.x;
  const int w = tid >> 6, lane = tid & 63, quad = lane >> 4, l15 = lane & 15;
  const int wy = w >> 1, wx = w & 1;
  const int m0 = blockIdx.x * 128, n0 = blockIdx.y * 128;
  const int z = blockIdx.z;
  const unsigned short* Bt = Wt + (size_t)z * (512 * 768);

  f32x4 acc[4][4];
#pragma unroll
  for (int i = 0; i < 4; ++i)
#pragma unroll
    for (int j = 0; j < 4; ++j) acc[i][j] = (f32x4){0.f, 0.f, 0.f, 0.f};

  for (int k0 = 0; k0 < 768; k0 += 32) {
    __syncthreads();
#pragma unroll
    for (int s = 0; s < 2; ++s) {
      const int t = s * 256 + tid;
      gld16(A + (size_t)(m0 + (t >> 2)) * 768 + k0 + (t & 3) * 8,
            Al + s * 2048 + w * 512);
      gld16(Bt + (size_t)(n0 + (t >> 2)) * 768 + k0 + (t & 3) * 8,
            Bl + s * 2048 + w * 512);
    }
    __syncthreads();
    short8 af[4], bf[4];
#pragma unroll
    for (int i = 0; i < 4; ++i) {
      af[i] = *(const short8*)(Al + (wy * 64 + i * 16 + l15) * 32 + quad * 8);
      bf[i] = *(const short8*)(Bl + (wx * 64 + i * 16 + l15) * 32 + quad * 8);
    }
    if (z == 2) {
      // normal: rows m (nseq), cols n (d)
#pragma unroll
      for (int i = 0; i < 4; ++i)
#pragma unroll
        for (int j = 0; j < 4; ++j)
          acc[i][j] = __builtin_amdgcn_mfma_f32_16x16x32_bf16(af[i], bf[j], acc[i][j], 0, 0, 0);
    } else {
      // swapped: acc = C^T, rows n (d), cols m (nseq)
#pragma unroll
      for (int i = 0; i < 4; ++i)
#pragma unroll
        for (int j = 0; j < 4; ++j)
          acc[i][j] = __builtin_amdgcn_mfma_f32_16x16x32_bf16(bf[i], af[j], acc[i][j], 0, 0, 0);
    }
  }

  if (z == 2) {
#pragma unroll
    for (int i = 0; i < 4; ++i) {
#pragma unroll
      for (int j = 0; j < 4; ++j) {
        const int m0r = m0 + wy * 64 + i * 16 + quad * 4;  // key0 (4-aligned)
        const int n = n0 + wx * 64 + j * 16 + l15;         // inner dim
        const int b = m0r >> 12, nseq0 = m0r & 4095;
        const int h = n >> 6, d0 = n & 63;
        const int kti = nseq0 >> 5, kc = (nseq0 >> 4) & 1;
        const int hv = (nseq0 >> 3) & 1, e0 = nseq0 & 7;   // e0 in {0,4}
        const int dt = (d0 >> 5) & 1, lv = hv * 32 + (d0 & 31);
        ushort4 u;
        u.x = f2bf(acc[i][j][0]); u.y = f2bf(acc[i][j][1]);
        u.z = f2bf(acc[i][j][2]); u.w = f2bf(acc[i][j][3]);
        *(ushort4*)(vtb + (size_t)(b * 8 + h) * 262144 +
                    ((((kti * 2 + dt) * 2 + kc) * 64 + lv) * 8 + e0)) = u;
      }
    }
  } else {
    const float qs = 0.18033688011112042f;  // 0.125*log2(e), z==0 only
#pragma unroll
    for (int i = 0; i < 4; ++i) {
#pragma unroll
      for (int j = 0; j < 4; ++j) {
        const int n0r = n0 + wx * 64 + i * 16 + quad * 4;  // inner dim, r=0
        const int m = m0 + wy * 64 + j * 16 + l15;         // nseq
        const int b = m >> 12, nseq = m & 4095;
        const int h = n0r >> 6, d0 = n0r & 63;
        ushort4 u;
        if (z == 0) {
          u.x = f2bf(acc[i][j][0] * qs); u.y = f2bf(acc[i][j][1] * qs);
          u.z = f2bf(acc[i][j][2] * qs); u.w = f2bf(acc[i][j][3] * qs);
          *(ushort4*)(qb + (size_t)((b * 8 + h) * 4096 + nseq) * 64 + d0) = u;
        } else {
          // K fragment-tiled: d0..d0+3 live in one 8-elem group (d0%4==0)
          const int kti = nseq >> 5, l31k = nseq & 31;
          const int c = (d0 >> 4) & 3, hk = (d0 >> 3) & 1, e0 = d0 & 7;
          u.x = f2bf(acc[i][j][0]); u.y = f2bf(acc[i][j][1]);
          u.z = f2bf(acc[i][j][2]); u.w = f2bf(acc[i][j][3]);
          *(ushort4*)(kb + (size_t)(b * 8 + h) * 262144 +
                      (((kti * 4 + c) * 64 + (hk * 32 + l31k)) * 8 + e0)) = u;
        }
      }
    }
  }
}

// ---------------- flash attention (32x32x16, register P, hi-occupancy) ---
// 256 thr = 4 waves = 2 key-groups x 2 waves; one (b,h); 64 Q rows/block
// (R13), 32/wave. Group g handles keys [g*2048,(g+1)*2048). Grid 1024 =
// 4 blocks/CU -> 16 waves/CU at VGPR<=128 (__launch_bounds__(256,4));
// R12's 128-q blocks capped at 8 waves/CU with VALUBusy 53% (dep-chain
// stalls). L2 K/V traffic unchanged: 64 q-blocks/bh x 1MB = 1GB total.
//
// S^T = mfma32(K, Q): lane (l31,hi) holds S[key=(r&3)+8*(r>>2)+4*hi][q=l31].
// exp2 -> f32; row-sums in VALU (half-key partials + one shfl_xor(32)); P
// packs via v_cvt_pk_bf16_f32; cross-half shfl_xor(32) exchange places
// words into exact PV-A-frag order (lane-by-lane verified, R10-R12 passed).
//
// K/V loads: fragment-tiled layouts (see gemm_qkv_k) -> every load is a
// wave-contiguous lane-linear 1KB read. No explicit prefetch (R11: compiler
// collapses it; TLP at 16 waves/CU hides L2 latency). No LDS, no barriers
// in the main loop.
//
// bh XCD-swizzle: XCD = linear%8 round-robin; bh = 2*(L&7) + parity ->
// each XCD's K/V working set = 2 bh = 2MB, L2-resident.
// Merge of the 2 key-groups stays additive (static max); L and O bounce
// through LDS only in the epilogue.

__global__ __launch_bounds__(256, 4) void attn_k(
    const unsigned short* __restrict__ qb,   // [16][4096][64], pre-scaled
    const unsigned short* __restrict__ kb,   // [16][kti][c][lane][8] frag-tiled
    const unsigned short* __restrict__ vtb,  // [16][kti][dt][kc][lane][8]
    unsigned short* __restrict__ ob) {       // [2][4096][512]
  __shared__ __align__(16) char smem[17408];  // epilogue merge only
  const int tid = threadIdx.x;
  const int w = tid >> 6, lane = tid & 63;
  const int l31 = lane & 31, hi = lane >> 5;
  const int g = w >> 1, wq = w & 1;  // key-group, wave-in-group

  const int L = blockIdx.x + 64 * blockIdx.y;        // 0..1023
  const int bh = ((L & 7) << 1) | ((L >> 3) & 1);    // 2 bh per XCD
  const int q0 = (L >> 4) << 6;                      // 64-row q block

  const unsigned short* qbase = qb + (size_t)bh * (4096 * 64);
  const unsigned short* kbase = kb + (size_t)bh * 262144 + lane * 8;
  const unsigned short* vbase = vtb + (size_t)bh * 262144 + lane * 8;

  // Q fragments resident all kernel. B-frag: q=l31, d = c*16 + hi*8 + j.
  short8 qf[4];
  {
    const int qrow = q0 + wq * 32 + l31;
#pragma unroll
    for (int c = 0; c < 4; ++c)
      qf[c] = *(const short8*)(qbase + (size_t)qrow * 64 + c * 16 + hi * 8);
  }

  f32x16 Oacc[2];  // [dt]; D-layout: q=(r&3)+8*(r>>2)+4*hi, d=l31+32dt
#pragma unroll
  for (int dt = 0; dt < 2; ++dt)
#pragma unroll
    for (int r = 0; r < 16; ++r) Oacc[dt][r] = 0.f;
  float lsum = 0.f;  // per-lane: q=l31, keys of own hi-half

  const int jbase = g * 2048;

  for (int j0 = 0; j0 < 2048; j0 += 64) {
    const int kti0 = (jbase + j0) >> 5;
#pragma unroll
    for (int kt = 0; kt < 2; ++kt) {
      const int kti = kti0 + kt;
      short8 kf[4];
#pragma unroll
      for (int c = 0; c < 4; ++c)
        kf[c] = *(const short8*)(kbase + (size_t)(kti * 4 + c) * 512);
      short8 vf[2][2];
#pragma unroll
      for (int dt = 0; dt < 2; ++dt)
#pragma unroll
        for (int kc = 0; kc < 2; ++kc)
          vf[dt][kc] = *(const short8*)(vbase + (size_t)((kti * 2 + dt) * 2 + kc) * 512);

      f32x16 s;
#pragma unroll
      for (int r = 0; r < 16; ++r) s[r] = 0.f;
#pragma unroll
      for (int c = 0; c < 4; ++c)
        s = __builtin_amdgcn_mfma_f32_32x32x16_bf16(kf[c], qf[c], s, 0, 0, 0);

      float e[16];
#pragma unroll
      for (int r = 0; r < 16; ++r) e[r] = fast_exp2(s[r]);
      lsum += (((e[0] + e[1]) + (e[2] + e[3])) + ((e[4] + e[5]) + (e[6] + e[7]))) +
              (((e[8] + e[9]) + (e[10] + e[11])) + ((e[12] + e[13]) + (e[14] + e[15])));

      // pack key pairs: wv[g2*2+p] holds keys (8g2+4hi+2p, +1) for q=l31
      unsigned int wv[8];
#pragma unroll
      for (int g2 = 0; g2 < 4; ++g2)
#pragma unroll
        for (int p = 0; p < 2; ++p)
          wv[g2 * 2 + p] = cvtpk_bf16(e[4 * g2 + 2 * p], e[4 * g2 + 2 * p + 1]);

      // cross-half exchange (verified lane-by-lane, R10-R12 passed):
      //   hi0 sends wv[4kc+2..3], hi1 sends wv[4kc+0..1]
      const unsigned int s0 = hi ? wv[0] : wv[2];
      const unsigned int s1 = hi ? wv[1] : wv[3];
      const unsigned int s2 = hi ? wv[4] : wv[6];
      const unsigned int s3 = hi ? wv[5] : wv[7];
      const unsigned int x0 = __shfl_xor(s0, 32, 64);
      const unsigned int x1 = __shfl_xor(s1, 32, 64);
      const unsigned int x2 = __shfl_xor(s2, 32, 64);
      const unsigned int x3 = __shfl_xor(s3, 32, 64);
      // A-frag word Wp = keys {16kc + 8hi + 2p, +1}
      uint4v pa[2];
      pa[0] = (uint4v){hi ? x0 : wv[0], hi ? x1 : wv[1],
                       hi ? wv[2] : x0, hi ? wv[3] : x1};
      pa[1] = (uint4v){hi ? x2 : wv[4], hi ? x3 : wv[5],
                       hi ? wv[6] : x2, hi ? wv[7] : x3};

      // O += P V
#pragma unroll
      for (int dt = 0; dt < 2; ++dt)
#pragma unroll
        for (int kc = 0; kc < 2; ++kc)
          Oacc[dt] = __builtin_amdgcn_mfma_f32_32x32x16_bf16(
              __builtin_bit_cast(short8, pa[kc]), vf[dt][kc], Oacc[dt], 0, 0, 0);
    }
  }

  // per-q total L: combine complementary hi-halves (both halves end identical)
  const float lt = lsum + __shfl_xor(lsum, 32, 64);

  // ----- merge the two key-groups (additive: static max) -----
  __syncthreads();                      // all compute done; smem usable
  float* Ox = (float*)smem;             // [64][66] fp32 (pad 2)
  float* Lx = (float*)(smem + 16896);   // [2][64]
  Lx[g * 64 + wq * 32 + l31] = lt;      // dup x2 benign
  if (g == 1) {
#pragma unroll
    for (int dt = 0; dt < 2; ++dt)
#pragma unroll
      for (int r = 0; r < 16; ++r) {
        const int row = wq * 32 + (r & 3) + 8 * (r >> 2) + 4 * hi;
        Ox[row * 66 + dt * 32 + l31] = Oacc[dt][r];
      }
  }
  __syncthreads();
  if (g == 0) {
    const int b = bh >> 3, h = bh & 7;
#pragma unroll
    for (int r = 0; r < 16; ++r) {
      const int row = wq * 32 + (r & 3) + 8 * (r >> 2) + 4 * hi;
      const float inv = 1.0f / (Lx[row] + Lx[64 + row]);
#pragma unroll
      for (int dt = 0; dt < 2; ++dt)
        ob[(size_t)(b * 4096 + q0 + row) * 512 + h * 64 + dt * 32 + l31] =
            f2bf((Oacc[dt][r] + Ox[row * 66 + dt * 32 + l31]) * inv);
    }
  }
}

// ---------------- output projection GEMM ----------------
// 128x64 tiles, SWAPPED mfma (C^T) so lane's 4 r-values are 4 consecutive
// out-cols at fixed row -> one float4 store (+ float4 bias load).

__global__ __launch_bounds__(256) void gemm_out_k(
    const unsigned short* __restrict__ A,    // o [8192][512]
    const unsigned short* __restrict__ Bt,   // WoT [768][512]
    const float* __restrict__ bias, float* __restrict__ out) {
  __shared__ __align__(16) short Al[4096];  // [128][32]
  __shared__ __align__(16) short Bl[2048];  // [64][32]
  const int tid = threadIdx.x;
  const int w = tid >> 6, lane = tid & 63, quad = lane >> 4, l15 = lane & 15;
  const int m0 = blockIdx.x * 128, n0 = blockIdx.y * 64;

  f32x4 acc[2][4];
#pragma unroll
  for (int i = 0; i < 2; ++i)
#pragma unroll
    for (int j = 0; j < 4; ++j) acc[i][j] = (f32x4){0.f, 0.f, 0.f, 0.f};

  for (int k0 = 0; k0 < 512; k0 += 32) {
    __syncthreads();
#pragma unroll
    for (int s = 0; s < 2; ++s) {
      const int t = s * 256 + tid;
      gld16(A + (size_t)(m0 + (t >> 2)) * 512 + k0 + (t & 3) * 8,
            Al + s * 2048 + w * 512);
    }
    gld16(Bt + (size_t)(n0 + (tid >> 2)) * 512 + k0 + (tid & 3) * 8,
          Bl + w * 512);
    __syncthreads();
    short8 af[2], bf[4];
#pragma unroll
    for (int i = 0; i < 2; ++i)
      af[i] = *(const short8*)(Al + (w * 32 + i * 16 + l15) * 32 + quad * 8);
#pragma unroll
    for (int j = 0; j < 4; ++j)
      bf[j] = *(const short8*)(Bl + (j * 16 + l15) * 32 + quad * 8);
    // swapped: acc[i][j] rows = out-col chunk j, cols = m chunk i
#pragma unroll
    for (int i = 0; i < 2; ++i)
#pragma unroll
      for (int j = 0; j < 4; ++j)
        acc[i][j] = __builtin_amdgcn_mfma_f32_16x16x32_bf16(bf[j], af[i], acc[i][j], 0, 0, 0);
  }

#pragma unroll
  for (int i = 0; i < 2; ++i) {
#pragma unroll
    for (int j = 0; j < 4; ++j) {
      const int col0 = n0 + j * 16 + quad * 4;
      const int m = m0 + w * 32 + i * 16 + l15;
      const float4 b4 = *(const float4*)(bias + col0);
      float4 o;
      o.x = acc[i][j][0] + b4.x; o.y = acc[i][j][1] + b4.y;
      o.z = acc[i][j][2] + b4.z; o.w = acc[i][j][3] + b4.w;
      *(float4*)(out + (size_t)m * 768 + col0) = o;
    }
  }
}

// ---------------- launch ----------------

extern "C" void kernel_launch(void* const* d_in, const int* in_sizes, int n_in,
                              void* d_out, int out_size, void* d_ws, size_t ws_size,
                              hipStream_t stream) {
  const float* x    = (const float*)d_in[0];
  const float* Wq   = (const float*)d_in[1];
  const float* Wk   = (const float*)d_in[2];
  const float* Wv   = (const float*)d_in[3];
  const float* Wout = (const float*)d_in[4];
  const float* bout = (const float*)d_in[5];
  float* out = (float*)d_out;
  char* ws = (char*)d_ws;

  // ws layout (bytes), total 49,283,072
  unsigned short* xb  = (unsigned short*)(ws);              // 12,582,912
  unsigned short* Wt  = (unsigned short*)(ws + 12582912);   //  2,359,296
  unsigned short* WoT = (unsigned short*)(ws + 14942208);   //    786,432
  unsigned short* qb  = (unsigned short*)(ws + 15728640);   //  8,388,608
  unsigned short* kb  = (unsigned short*)(ws + 24117248);   //  8,388,608
  unsigned short* vtb = (unsigned short*)(ws + 32505856);   //  8,388,608
  unsigned short* ob  = (unsigned short*)(ws + 40894464);   //  8,388,608

  cvt_x_k<<<6144, 256, 0, stream>>>(x, xb);
  transpose_w_k<<<dim3(24, 24, 4), 256, 0, stream>>>(Wq, Wk, Wv, Wout, Wt, WoT);
  gemm_qkv_k<<<dim3(64, 4, 3), 256, 0, stream>>>(xb, Wt, qb, kb, vtb);
  attn_k<<<dim3(64, 16), 256, 0, stream>>>(qb, kb, vtb, ob);
  gemm_out_k<<<dim3(64, 12), 256, 0, stream>>>(ob, WoT, bout, out);
}

// Round 10
// 242.373 us; speedup vs baseline: 1.0424x; 1.0424x over previous
//
#include <hip/hip_runtime.h>
#include <cstdint>
#include <cstddef>

// B=2, N=4096, QDIM=768, H=8, D=64, INNER=512
// Pipeline: cvt x->bf16; LDS-tiled weight transposes; QKV gemm (bf16 MFMA)
// writing q[b,h,n,d] (pre-scaled by 0.125*log2e) and K/V in MFMA-FRAGMENT-
// TILED layouts (R12: attention loads are wave-contiguous 1KB reads);
// flash attention (R16 = R12-verified structure + MFMA ones-trick L):
// 128-q blocks, 2 key-groups x 2 q-waves (grid 512); 32x32x16 MFMA, swapped
// QK^T, register-resident P (cvt_pk_bf16 + verified shfl_xor(32) exchange);
// row-sums via MFMA ones-column (R0-verified technique) instead of VALU
// chain -- moves ~64cy/kt off the 53%-busy VALU pipe onto the 34%-busy
// MFMA pipe, and L derives from the same bf16 P as PV. [R14/R15's 4-way
// key-split failed 2x at ~0.095 with two different provably-distinct
// merges -- topology abandoned, cause unidentified.]
// XCD-swizzled bh (2 bh = 2MB per XCD, L2-resident);
// out gemm + bias (C^T, float4 stores) -> fp32.

typedef __attribute__((ext_vector_type(8))) short short8;
typedef __attribute__((ext_vector_type(4))) float f32x4;
typedef __attribute__((ext_vector_type(16))) float f32x16;
typedef __attribute__((ext_vector_type(4))) unsigned int uint4v;

__device__ __forceinline__ unsigned short f2bf(float f) {
  // round-to-nearest-even bf16 (truncation's systematic -2^-9 bias through
  // 3 GEMM stages would blow the threshold)
  unsigned int u = __float_as_uint(f);
  u = (u + 0x7fffu + ((u >> 16) & 1u)) >> 16;
  return (unsigned short)u;
}

__device__ __forceinline__ float fast_exp2(float x) {
#if __has_builtin(__builtin_amdgcn_exp2f)
  return __builtin_amdgcn_exp2f(x);  // raw v_exp_f32
#else
  return __expf(x * 0.69314718055994531f);  // e^(x ln2) = 2^x
#endif
}

__device__ __forceinline__ void gld16(const void* g, void* l) {
  // async global->LDS, 16B/lane; LDS dest = wave-uniform base + lane*16
  __builtin_amdgcn_global_load_lds(
      (__attribute__((address_space(1))) void*)const_cast<void*>(g),
      (__attribute__((address_space(3))) void*)l, 16, 0, 0);
}

__device__ __forceinline__ unsigned int cvtpk_bf16(float lo, float hi) {
  // {lo16 = bf16_rne(lo), hi16 = bf16_rne(hi)} — single VALU op.
  // HW-verified in R11/R12 (passed, absmax matches bit-op RNE path).
  unsigned int r;
  asm("v_cvt_pk_bf16_f32 %0, %1, %2" : "=v"(r) : "v"(lo), "v"(hi));
  return r;
}

// ---------------- prep kernels ----------------

__global__ __launch_bounds__(256) void cvt_x_k(const float* __restrict__ x,
                                               unsigned short* __restrict__ xb) {
  const size_t i = ((size_t)blockIdx.x * 256 + threadIdx.x) * 4;  // 6291456 elems
  const float4 v = *(const float4*)(x + i);
  ushort4 u;
  u.x = f2bf(v.x); u.y = f2bf(v.y); u.z = f2bf(v.z); u.w = f2bf(v.w);
  *(ushort4*)(xb + i) = u;
}

// One LDS-tiled transpose for all 4 weight matrices. fp32 [R][C] -> bf16 [C][R].
__global__ __launch_bounds__(256) void transpose_w_k(
    const float* __restrict__ Wq, const float* __restrict__ Wk,
    const float* __restrict__ Wv, const float* __restrict__ Wout,
    unsigned short* __restrict__ Wt,   // [3][512][768]
    unsigned short* __restrict__ WoT)  // [768][512]
{
  __shared__ float t[32][33];  // +1 pad: conflict-free transpose
  const int z = blockIdx.z;    // 0..2: Wq/Wk/Wv (768x512); 3: Wout (512x768)
  const float* src = (z == 0) ? Wq : (z == 1) ? Wk : (z == 2) ? Wv : Wout;
  const int R = (z < 3) ? 768 : 512, C = (z < 3) ? 512 : 768;
  unsigned short* dst = (z < 3) ? (Wt + (size_t)z * 393216) : WoT;
  const int tx = threadIdx.x & 31, ty = threadIdx.x >> 5;  // 32 x 8
  const int c0 = blockIdx.x * 32, r0 = blockIdx.y * 32;
  if (c0 >= C || r0 >= R) return;
#pragma unroll
  for (int k = 0; k < 4; ++k)
    t[ty + 8 * k][tx] = src[(size_t)(r0 + ty + 8 * k) * C + c0 + tx];
  __syncthreads();
#pragma unroll
  for (int k = 0; k < 4; ++k)
    dst[(size_t)(c0 + ty + 8 * k) * R + r0 + tx] = f2bf(t[tx][ty + 8 * k]);
}

// ---------------- QKV projection GEMM ----------------
// C[8192][512] = xb[8192][768] @ Wt[z]^T ; packed-store epilogues:
// z=0 (q, layout [bh][nseq][d]): SWAPPED mfma -> C^T, lane's 4 r-values are
//   4 consecutive d at fixed nseq -> one ushort4; pre-scaled 0.125*log2(e).
// z=1 (k, FRAGMENT-TILED [bh][kti][c][lane][8], kti=32-key tile,
//   lane=hi*32+l31): lane's 4 r-values are d0..d0+3 at fixed key; c=d>>4,
//   hi=(d>>3)&1, l31=key&31, e0=d0&7 in {0,4} -> one 8B-aligned ushort4.
// z=2 (v, FRAGMENT-TILED [bh][kti][dt][kc][lane][8], lane=hi*32+(d&31)):
//   NORMAL mfma, lane's 4 r-values are key0..key0+3 at fixed d; kc=
//   (key>>4)&1, hi=(key>>3)&1, dt=(d>>5)&1, e0=key0&7 -> one ushort4.
// These layouts make every attention K/V fragment load a wave-contiguous
// 1KB global read (lane-linear): R12 took attn 142 -> 88us with them.

__global__ __launch_bounds__(256) void gemm_qkv_k(
    const unsigned short* __restrict__ A,    // xb [8192][768]
    const unsigned short* __restrict__ Wt,   // [3][512][768]
    unsigned short* __restrict__ qb, unsigned short* __restrict__ kb,
    unsigned short* __restrict__ vtb) {
  __shared__ __align__(16) short Al[4096];  // [128][32]
  __shared__ __align__(16) short Bl[4096];  // [128][32]
  const int tid = threadIdx.x;
  const int w = tid >> 6, lane = tid & 63, quad = lane >> 4, l15 = lane & 15;
  const int wy = w >> 1, wx = w & 1;
  const int m0 = blockIdx.x * 128, n0 = blockIdx.y * 128;
  const int z = blockIdx.z;
  const unsigned short* Bt = Wt + (size_t)z * (512 * 768);

  f32x4 acc[4][4];
#pragma unroll
  for (int i = 0; i < 4; ++i)
#pragma unroll
    for (int j = 0; j < 4; ++j) acc[i][j] = (f32x4){0.f, 0.f, 0.f, 0.f};

  for (int k0 = 0; k0 < 768; k0 += 32) {
    __syncthreads();
#pragma unroll
    for (int s = 0; s < 2; ++s) {
      const int t = s * 256 + tid;
      gld16(A + (size_t)(m0 + (t >> 2)) * 768 + k0 + (t & 3) * 8,
            Al + s * 2048 + w * 512);
      gld16(Bt + (size_t)(n0 + (t >> 2)) * 768 + k0 + (t & 3) * 8,
            Bl + s * 2048 + w * 512);
    }
    __syncthreads();
    short8 af[4], bf[4];
#pragma unroll
    for (int i = 0; i < 4; ++i) {
      af[i] = *(const short8*)(Al + (wy * 64 + i * 16 + l15) * 32 + quad * 8);
      bf[i] = *(const short8*)(Bl + (wx * 64 + i * 16 + l15) * 32 + quad * 8);
    }
    if (z == 2) {
      // normal: rows m (nseq), cols n (d)
#pragma unroll
      for (int i = 0; i < 4; ++i)
#pragma unroll
        for (int j = 0; j < 4; ++j)
          acc[i][j] = __builtin_amdgcn_mfma_f32_16x16x32_bf16(af[i], bf[j], acc[i][j], 0, 0, 0);
    } else {
      // swapped: acc = C^T, rows n (d), cols m (nseq)
#pragma unroll
      for (int i = 0; i < 4; ++i)
#pragma unroll
        for (int j = 0; j < 4; ++j)
          acc[i][j] = __builtin_amdgcn_mfma_f32_16x16x32_bf16(bf[i], af[j], acc[i][j], 0, 0, 0);
    }
  }

  if (z == 2) {
#pragma unroll
    for (int i = 0; i < 4; ++i) {
#pragma unroll
      for (int j = 0; j < 4; ++j) {
        const int m0r = m0 + wy * 64 + i * 16 + quad * 4;  // key0 (4-aligned)
        const int n = n0 + wx * 64 + j * 16 + l15;         // inner dim
        const int b = m0r >> 12, nseq0 = m0r & 4095;
        const int h = n >> 6, d0 = n & 63;
        const int kti = nseq0 >> 5, kc = (nseq0 >> 4) & 1;
        const int hv = (nseq0 >> 3) & 1, e0 = nseq0 & 7;   // e0 in {0,4}
        const int dt = (d0 >> 5) & 1, lv = hv * 32 + (d0 & 31);
        ushort4 u;
        u.x = f2bf(acc[i][j][0]); u.y = f2bf(acc[i][j][1]);
        u.z = f2bf(acc[i][j][2]); u.w = f2bf(acc[i][j][3]);
        *(ushort4*)(vtb + (size_t)(b * 8 + h) * 262144 +
                    ((((kti * 2 + dt) * 2 + kc) * 64 + lv) * 8 + e0)) = u;
      }
    }
  } else {
    const float qs = 0.18033688011112042f;  // 0.125*log2(e), z==0 only
#pragma unroll
    for (int i = 0; i < 4; ++i) {
#pragma unroll
      for (int j = 0; j < 4; ++j) {
        const int n0r = n0 + wx * 64 + i * 16 + quad * 4;  // inner dim, r=0
        const int m = m0 + wy * 64 + j * 16 + l15;         // nseq
        const int b = m >> 12, nseq = m & 4095;
        const int h = n0r >> 6, d0 = n0r & 63;
        ushort4 u;
        if (z == 0) {
          u.x = f2bf(acc[i][j][0] * qs); u.y = f2bf(acc[i][j][1] * qs);
          u.z = f2bf(acc[i][j][2] * qs); u.w = f2bf(acc[i][j][3] * qs);
          *(ushort4*)(qb + (size_t)((b * 8 + h) * 4096 + nseq) * 64 + d0) = u;
        } else {
          // K fragment-tiled: d0..d0+3 live in one 8-elem group (d0%4==0)
          const int kti = nseq >> 5, l31k = nseq & 31;
          const int c = (d0 >> 4) & 3, hk = (d0 >> 3) & 1, e0 = d0 & 7;
          u.x = f2bf(acc[i][j][0]); u.y = f2bf(acc[i][j][1]);
          u.z = f2bf(acc[i][j][2]); u.w = f2bf(acc[i][j][3]);
          *(ushort4*)(kb + (size_t)(b * 8 + h) * 262144 +
                      (((kti * 4 + c) * 64 + (hk * 32 + l31k)) * 8 + e0)) = u;
        }
      }
    }
  }
}

// ---------------- flash attention (32x32x16, register P, R12 structure) --
// 256 thr = 4 waves = 2 key-groups x 2 waves; one (b,h); 128 Q rows/block,
// 64/wave (2 q-subtiles of 32). Group g handles keys [g*2048,(g+1)*2048).
// Grid 512 = 32 q-blocks x 16 bh (the R12-verified 87.9us configuration).
//
// S^T = mfma32(K, Q): lane (l31,hi) holds S[key=(r&3)+8*(r>>2)+4*hi][q=l31].
// exp2 -> f32; P packs via v_cvt_pk_bf16_f32; cross-half shfl_xor(32)
// exchange places words into exact PV-A-frag order (R10-R13 verified).
// Row-sums L via MFMA ones-column (R0-verified): Lacc += mfma(pa, vones)
// -- L derives from the same bf16 P as PV; removes the 32-add VALU chain
// per kt (R12 was VALU-bound: 53% busy vs 34% MFMA).
//
// K/V loads: fragment-tiled layouts (see gemm_qkv_k) -> every load is a
// wave-contiguous lane-linear 1KB read. No LDS, no barriers in main loop.
//
// bh XCD-swizzle: XCD = linear%8 round-robin; bh = 2*(L&7) + parity ->
// each XCD's K/V working set = 2 bh = 2MB, L2-resident.
//
// Merge (additive, static max): g=1 writes Ox + one Lg1 strip; g=0 adds,
// normalizes with register-resident Lacc + Lg1, stores. 34304B LDS.

__global__ __launch_bounds__(256) void attn_k(
    const unsigned short* __restrict__ qb,   // [16][4096][64], pre-scaled
    const unsigned short* __restrict__ kb,   // [16][kti][c][lane][8] frag-tiled
    const unsigned short* __restrict__ vtb,  // [16][kti][dt][kc][lane][8]
    unsigned short* __restrict__ ob) {       // [2][4096][512]
  __shared__ __align__(16) char smem[34304];  // epilogue merge only
  const int tid = threadIdx.x;
  const int w = tid >> 6, lane = tid & 63;
  const int l31 = lane & 31, hi = lane >> 5;
  const int g = w >> 1, wq = w & 1;  // key-group, wave-in-group

  const int L = blockIdx.x + 32 * blockIdx.y;        // 0..511
  const int bh = ((L & 7) << 1) | ((L >> 3) & 1);    // 2 bh per XCD
  const int q0 = (L >> 4) << 7;                      // 128-row q block

  const unsigned short* qbase = qb + (size_t)bh * (4096 * 64);
  const unsigned short* kbase = kb + (size_t)bh * 262144 + lane * 8;
  const unsigned short* vbase = vtb + (size_t)bh * 262144 + lane * 8;

  // Q fragments resident all kernel. B-frag: q=l31, d = c*16 + hi*8 + j.
  short8 qf[2][4];
#pragma unroll
  for (int qs = 0; qs < 2; ++qs) {
    const int qrow = q0 + wq * 64 + qs * 32 + l31;
#pragma unroll
    for (int c = 0; c < 4; ++c)
      qf[qs][c] = *(const short8*)(qbase + (size_t)qrow * 64 + c * 16 + hi * 8);
  }

  // ones B-fragment: L = P @ ones gives row sums in every output column
  const short one_bf = (short)0x3F80;
  const short8 vones = {one_bf, one_bf, one_bf, one_bf,
                        one_bf, one_bf, one_bf, one_bf};

  f32x16 Oacc[2][2];  // [qs][dt]; D-layout: q=(r&3)+8*(r>>2)+4*hi, d=l31+32dt
#pragma unroll
  for (int qs = 0; qs < 2; ++qs)
#pragma unroll
    for (int dt = 0; dt < 2; ++dt)
#pragma unroll
      for (int r = 0; r < 16; ++r) Oacc[qs][dt][r] = 0.f;
  f32x16 Lacc[2];  // [qs]; all cols identical = row sum
#pragma unroll
  for (int qs = 0; qs < 2; ++qs)
#pragma unroll
    for (int r = 0; r < 16; ++r) Lacc[qs][r] = 0.f;

  const int jbase = g * 2048;

  for (int j0 = 0; j0 < 2048; j0 += 64) {
    const int kti0 = (jbase + j0) >> 5;
#pragma unroll
    for (int kt = 0; kt < 2; ++kt) {
      const int kti = kti0 + kt;
      short8 kf[4];
#pragma unroll
      for (int c = 0; c < 4; ++c)
        kf[c] = *(const short8*)(kbase + (size_t)(kti * 4 + c) * 512);
      short8 vf[2][2];
#pragma unroll
      for (int dt = 0; dt < 2; ++dt)
#pragma unroll
        for (int kc = 0; kc < 2; ++kc)
          vf[dt][kc] = *(const short8*)(vbase + (size_t)((kti * 2 + dt) * 2 + kc) * 512);

      uint4v pa[2][2];  // [qs][kc] PV A-frags (packed bf16 pairs)
#pragma unroll
      for (int qs = 0; qs < 2; ++qs) {
        f32x16 s;
#pragma unroll
        for (int r = 0; r < 16; ++r) s[r] = 0.f;
#pragma unroll
        for (int c = 0; c < 4; ++c)
          s = __builtin_amdgcn_mfma_f32_32x32x16_bf16(kf[c], qf[qs][c], s, 0, 0, 0);

        float e[16];
#pragma unroll
        for (int r = 0; r < 16; ++r) e[r] = fast_exp2(s[r]);

        // pack key pairs: wv[g2*2+p] holds keys (8g2+4hi+2p, +1) for q=l31
        unsigned int wv[8];
#pragma unroll
        for (int g2 = 0; g2 < 4; ++g2)
#pragma unroll
          for (int p = 0; p < 2; ++p)
            wv[g2 * 2 + p] = cvtpk_bf16(e[4 * g2 + 2 * p], e[4 * g2 + 2 * p + 1]);

        // cross-half exchange (verified lane-by-lane, R10-R13 passed):
        //   hi0 sends wv[4kc+2..3], hi1 sends wv[4kc+0..1]
        const unsigned int s0 = hi ? wv[0] : wv[2];
        const unsigned int s1 = hi ? wv[1] : wv[3];
        const unsigned int s2 = hi ? wv[4] : wv[6];
        const unsigned int s3 = hi ? wv[5] : wv[7];
        const unsigned int x0 = __shfl_xor(s0, 32, 64);
        const unsigned int x1 = __shfl_xor(s1, 32, 64);
        const unsigned int x2 = __shfl_xor(s2, 32, 64);
        const unsigned int x3 = __shfl_xor(s3, 32, 64);
        // A-frag word Wp = keys {16kc + 8hi + 2p, +1}
        pa[qs][0] = (uint4v){hi ? x0 : wv[0], hi ? x1 : wv[1],
                             hi ? wv[2] : x0, hi ? wv[3] : x1};
        pa[qs][1] = (uint4v){hi ? x2 : wv[4], hi ? x3 : wv[5],
                             hi ? wv[6] : x2, hi ? wv[7] : x3};
      }

      // O += P V ; L += P @ ones  (V-frags reused by both q-subtiles)
#pragma unroll
      for (int dt = 0; dt < 2; ++dt)
#pragma unroll
        for (int kc = 0; kc < 2; ++kc)
#pragma unroll
          for (int qs = 0; qs < 2; ++qs)
            Oacc[qs][dt] = __builtin_amdgcn_mfma_f32_32x32x16_bf16(
                __builtin_bit_cast(short8, pa[qs][kc]), vf[dt][kc], Oacc[qs][dt], 0, 0, 0);
#pragma unroll
      for (int kc = 0; kc < 2; ++kc)
#pragma unroll
        for (int qs = 0; qs < 2; ++qs)
          Lacc[qs] = __builtin_amdgcn_mfma_f32_32x32x16_bf16(
              __builtin_bit_cast(short8, pa[qs][kc]), vones, Lacc[qs], 0, 0, 0);
    }
  }

  // ----- merge the two key-groups (additive: static max) -----
  __syncthreads();                      // all compute done; smem usable
  float* Ox  = (float*)smem;            // [128][66] fp32 (pad 2) = 33792 B
  float* Lg1 = (float*)(smem + 33792);  // [128] = 512 B
  if (g == 1) {
#pragma unroll
    for (int qs = 0; qs < 2; ++qs)
#pragma unroll
      for (int r = 0; r < 16; ++r) {
        const int row = wq * 64 + qs * 32 + (r & 3) + 8 * (r >> 2) + 4 * hi;
        Lg1[row] = Lacc[qs][r];  // all 32 cols identical -> benign dup
#pragma unroll
        for (int dt = 0; dt < 2; ++dt)
          Ox[row * 66 + dt * 32 + l31] = Oacc[qs][dt][r];
      }
  }
  __syncthreads();
  if (g == 0) {
    const int b = bh >> 3, h = bh & 7;
#pragma unroll
    for (int qs = 0; qs < 2; ++qs)
#pragma unroll
      for (int r = 0; r < 16; ++r) {
        const int row = wq * 64 + qs * 32 + (r & 3) + 8 * (r >> 2) + 4 * hi;
        const float inv = 1.0f / (Lacc[qs][r] + Lg1[row]);
#pragma unroll
        for (int dt = 0; dt < 2; ++dt)
          ob[(size_t)(b * 4096 + q0 + row) * 512 + h * 64 + dt * 32 + l31] =
              f2bf((Oacc[qs][dt][r] + Ox[row * 66 + dt * 32 + l31]) * inv);
      }
  }
}

// ---------------- output projection GEMM ----------------
// 128x64 tiles, SWAPPED mfma (C^T) so lane's 4 r-values are 4 consecutive
// out-cols at fixed row -> one float4 store (+ float4 bias load).

__global__ __launch_bounds__(256) void gemm_out_k(
    const unsigned short* __restrict__ A,    // o [8192][512]
    const unsigned short* __restrict__ Bt,   // WoT [768][512]
    const float* __restrict__ bias, float* __restrict__ out) {
  __shared__ __align__(16) short Al[4096];  // [128][32]
  __shared__ __align__(16) short Bl[2048];  // [64][32]
  const int tid = threadIdx.x;
  const int w = tid >> 6, lane = tid & 63, quad = lane >> 4, l15 = lane & 15;
  const int m0 = blockIdx.x * 128, n0 = blockIdx.y * 64;

  f32x4 acc[2][4];
#pragma unroll
  for (int i = 0; i < 2; ++i)
#pragma unroll
    for (int j = 0; j < 4; ++j) acc[i][j] = (f32x4){0.f, 0.f, 0.f, 0.f};

  for (int k0 = 0; k0 < 512; k0 += 32) {
    __syncthreads();
#pragma unroll
    for (int s = 0; s < 2; ++s) {
      const int t = s * 256 + tid;
      gld16(A + (size_t)(m0 + (t >> 2)) * 512 + k0 + (t & 3) * 8,
            Al + s * 2048 + w * 512);
    }
    gld16(Bt + (size_t)(n0 + (tid >> 2)) * 512 + k0 + (tid & 3) * 8,
          Bl + w * 512);
    __syncthreads();
    short8 af[2], bf[4];
#pragma unroll
    for (int i = 0; i < 2; ++i)
      af[i] = *(const short8*)(Al + (w * 32 + i * 16 + l15) * 32 + quad * 8);
#pragma unroll
    for (int j = 0; j < 4; ++j)
      bf[j] = *(const short8*)(Bl + (j * 16 + l15) * 32 + quad * 8);
    // swapped: acc[i][j] rows = out-col chunk j, cols = m chunk i
#pragma unroll
    for (int i = 0; i < 2; ++i)
#pragma unroll
      for (int j = 0; j < 4; ++j)
        acc[i][j] = __builtin_amdgcn_mfma_f32_16x16x32_bf16(bf[j], af[i], acc[i][j], 0, 0, 0);
  }

#pragma unroll
  for (int i = 0; i < 2; ++i) {
#pragma unroll
    for (int j = 0; j < 4; ++j) {
      const int col0 = n0 + j * 16 + quad * 4;
      const int m = m0 + w * 32 + i * 16 + l15;
      const float4 b4 = *(const float4*)(bias + col0);
      float4 o;
      o.x = acc[i][j][0] + b4.x; o.y = acc[i][j][1] + b4.y;
      o.z = acc[i][j][2] + b4.z; o.w = acc[i][j][3] + b4.w;
      *(float4*)(out + (size_t)m * 768 + col0) = o;
    }
  }
}

// ---------------- launch ----------------

extern "C" void kernel_launch(void* const* d_in, const int* in_sizes, int n_in,
                              void* d_out, int out_size, void* d_ws, size_t ws_size,
                              hipStream_t stream) {
  const float* x    = (const float*)d_in[0];
  const float* Wq   = (const float*)d_in[1];
  const float* Wk   = (const float*)d_in[2];
  const float* Wv   = (const float*)d_in[3];
  const float* Wout = (const float*)d_in[4];
  const float* bout = (const float*)d_in[5];
  float* out = (float*)d_out;
  char* ws = (char*)d_ws;

  // ws layout (bytes), total 49,283,072
  unsigned short* xb  = (unsigned short*)(ws);              // 12,582,912
  unsigned short* Wt  = (unsigned short*)(ws + 12582912);   //  2,359,296
  unsigned short* WoT = (unsigned short*)(ws + 14942208);   //    786,432
  unsigned short* qb  = (unsigned short*)(ws + 15728640);   //  8,388,608
  unsigned short* kb  = (unsigned short*)(ws + 24117248);   //  8,388,608
  unsigned short* vtb = (unsigned short*)(ws + 32505856);   //  8,388,608
  unsigned short* ob  = (unsigned short*)(ws + 40894464);   //  8,388,608

  cvt_x_k<<<6144, 256, 0, stream>>>(x, xb);
  transpose_w_k<<<dim3(24, 24, 4), 256, 0, stream>>>(Wq, Wk, Wv, Wout, Wt, WoT);
  gemm_qkv_k<<<dim3(64, 4, 3), 256, 0, stream>>>(xb, Wt, qb, kb, vtb);
  attn_k<<<dim3(32, 16), 256, 0, stream>>>(qb, kb, vtb, ob);
  gemm_out_k<<<dim3(64, 12), 256, 0, stream>>>(ob, WoT, bout, out);
}

// Round 11
// 215.841 us; speedup vs baseline: 1.1706x; 1.1229x over previous
//
#include <hip/hip_runtime.h>
#include <cstdint>
#include <cstddef>

// B=2, N=4096, QDIM=768, H=8, D=64, INNER=512
// Pipeline: cvt x->bf16; LDS-tiled weight transposes; QKV gemm (bf16 MFMA)
// writing q[b,h,n,d] (pre-scaled by 0.125*log2e) and K/V in MFMA-FRAGMENT-
// TILED layouts; V additionally K-PERMUTED (R17 zero-shuffle PV: V's k-slot
// order matches P's natural lane layout, so the PV A-frag needs NO cross-
// lane exchange -- removes 16 VALU ops/16-elems from R12's hot loop);
// flash attention = R12-verified structure (128-q blocks, 2 key-groups x
// 2 q-waves, grid 512): 32x32x16 MFMA, swapped QK^T, register-resident P
// (cvt_pk_bf16 pack), VALU row-sums, s_setprio(1) around MFMA clusters
// (T5); XCD-swizzled bh (2 bh = 2MB per XCD, L2-resident).
// [R16's MFMA ones-trick L regressed 88->119us: serial L-MFMA chain +32
// VGPR at 2 blocks/CU = dependency-bound, reverted. R14/R15 key-split
// abandoned (2x fail ~0.095, cause unidentified).]
// out gemm + bias (C^T, float4 stores) -> fp32.

typedef __attribute__((ext_vector_type(8))) short short8;
typedef __attribute__((ext_vector_type(4))) float f32x4;
typedef __attribute__((ext_vector_type(16))) float f32x16;
typedef __attribute__((ext_vector_type(4))) unsigned int uint4v;

__device__ __forceinline__ unsigned short f2bf(float f) {
  // round-to-nearest-even bf16 (truncation's systematic -2^-9 bias through
  // 3 GEMM stages would blow the threshold)
  unsigned int u = __float_as_uint(f);
  u = (u + 0x7fffu + ((u >> 16) & 1u)) >> 16;
  return (unsigned short)u;
}

__device__ __forceinline__ float fast_exp2(float x) {
#if __has_builtin(__builtin_amdgcn_exp2f)
  return __builtin_amdgcn_exp2f(x);  // raw v_exp_f32
#else
  return __expf(x * 0.69314718055994531f);  // e^(x ln2) = 2^x
#endif
}

__device__ __forceinline__ void gld16(const void* g, void* l) {
  // async global->LDS, 16B/lane; LDS dest = wave-uniform base + lane*16
  __builtin_amdgcn_global_load_lds(
      (__attribute__((address_space(1))) void*)const_cast<void*>(g),
      (__attribute__((address_space(3))) void*)l, 16, 0, 0);
}

__device__ __forceinline__ unsigned int cvtpk_bf16(float lo, float hi) {
  // {lo16 = bf16_rne(lo), hi16 = bf16_rne(hi)} — single VALU op.
  // HW-verified in R11/R12 (passed, absmax matches bit-op RNE path).
  unsigned int r;
  asm("v_cvt_pk_bf16_f32 %0, %1, %2" : "=v"(r) : "v"(lo), "v"(hi));
  return r;
}

// ---------------- prep kernels ----------------

__global__ __launch_bounds__(256) void cvt_x_k(const float* __restrict__ x,
                                               unsigned short* __restrict__ xb) {
  const size_t i = ((size_t)blockIdx.x * 256 + threadIdx.x) * 4;  // 6291456 elems
  const float4 v = *(const float4*)(x + i);
  ushort4 u;
  u.x = f2bf(v.x); u.y = f2bf(v.y); u.z = f2bf(v.z); u.w = f2bf(v.w);
  *(ushort4*)(xb + i) = u;
}

// One LDS-tiled transpose for all 4 weight matrices. fp32 [R][C] -> bf16 [C][R].
__global__ __launch_bounds__(256) void transpose_w_k(
    const float* __restrict__ Wq, const float* __restrict__ Wk,
    const float* __restrict__ Wv, const float* __restrict__ Wout,
    unsigned short* __restrict__ Wt,   // [3][512][768]
    unsigned short* __restrict__ WoT)  // [768][512]
{
  __shared__ float t[32][33];  // +1 pad: conflict-free transpose
  const int z = blockIdx.z;    // 0..2: Wq/Wk/Wv (768x512); 3: Wout (512x768)
  const float* src = (z == 0) ? Wq : (z == 1) ? Wk : (z == 2) ? Wv : Wout;
  const int R = (z < 3) ? 768 : 512, C = (z < 3) ? 512 : 768;
  unsigned short* dst = (z < 3) ? (Wt + (size_t)z * 393216) : WoT;
  const int tx = threadIdx.x & 31, ty = threadIdx.x >> 5;  // 32 x 8
  const int c0 = blockIdx.x * 32, r0 = blockIdx.y * 32;
  if (c0 >= C || r0 >= R) return;
#pragma unroll
  for (int k = 0; k < 4; ++k)
    t[ty + 8 * k][tx] = src[(size_t)(r0 + ty + 8 * k) * C + c0 + tx];
  __syncthreads();
#pragma unroll
  for (int k = 0; k < 4; ++k)
    dst[(size_t)(c0 + ty + 8 * k) * R + r0 + tx] = f2bf(t[tx][ty + 8 * k]);
}

// ---------------- QKV projection GEMM ----------------
// C[8192][512] = xb[8192][768] @ Wt[z]^T ; packed-store epilogues:
// z=0 (q, layout [bh][nseq][d]): SWAPPED mfma -> C^T, lane's 4 r-values are
//   4 consecutive d at fixed nseq -> one ushort4; pre-scaled 0.125*log2(e).
// z=1 (k, FRAGMENT-TILED [bh][kti][c][lane][8], kti=32-key tile,
//   lane=hi*32+l31): lane's 4 r-values are d0..d0+3 at fixed key; c=d>>4,
//   hi=(d>>3)&1, l31=key&31, e0=d0&7 in {0,4} -> one 8B-aligned ushort4.
// z=2 (v, FRAGMENT-TILED + K-PERMUTED [bh][kti][dt][kc][lane][8]):
//   R17: slot for key k is hiv=(k>>2)&1, eb=((k&15)>>3)*4+(k&3), chosen so
//   hardware B k-label pi(hiv,eb)=16kc+(eb>>2)*8+4hiv+(eb&3) equals P's
//   natural A-side label -> attention needs NO P exchange. 4 consecutive
//   keys (key0 4-aligned) still land in one 8B-aligned ushort4.
// These layouts make every attention K/V fragment load a wave-contiguous
// 1KB global read (lane-linear): R12 took attn 142 -> 88us with them.

__global__ __launch_bounds__(256) void gemm_qkv_k(
    const unsigned short* __restrict__ A,    // xb [8192][768]
    const unsigned short* __restrict__ Wt,   // [3][512][768]
    unsigned short* __restrict__ qb, unsigned short* __restrict__ kb,
    unsigned short* __restrict__ vtb) {
  __shared__ __align__(16) short Al[4096];  // [128][32]
  __shared__ __align__(16) short Bl[4096];  // [128][32]
  const int tid = threadIdx.x;
  const int w = tid >> 6, lane = tid & 63, quad = lane >> 4, l15 = lane & 15;
  const int wy = w >> 1, wx = w & 1;
  const int m0 = blockIdx.x * 128, n0 = blockIdx.y * 128;
  const int z = blockIdx.z;
  const unsigned short* Bt = Wt + (size_t)z * (512 * 768);

  f32x4 acc[4][4];
#pragma unroll
  for (int i = 0; i < 4; ++i)
#pragma unroll
    for (int j = 0; j < 4; ++j) acc[i][j] = (f32x4){0.f, 0.f, 0.f, 0.f};

  for (int k0 = 0; k0 < 768; k0 += 32) {
    __syncthreads();
#pragma unroll
    for (int s = 0; s < 2; ++s) {
      const int t = s * 256 + tid;
      gld16(A + (size_t)(m0 + (t >> 2)) * 768 + k0 + (t & 3) * 8,
            Al + s * 2048 + w * 512);
      gld16(Bt + (size_t)(n0 + (t >> 2)) * 768 + k0 + (t & 3) * 8,
            Bl + s * 2048 + w * 512);
    }
    __syncthreads();
    short8 af[4], bf[4];
#pragma unroll
    for (int i = 0; i < 4; ++i) {
      af[i] = *(const short8*)(Al + (wy * 64 + i * 16 + l15) * 32 + quad * 8);
      bf[i] = *(const short8*)(Bl + (wx * 64 + i * 16 + l15) * 32 + quad * 8);
    }
    if (z == 2) {
      // normal: rows m (nseq), cols n (d)
#pragma unroll
      for (int i = 0; i < 4; ++i)
#pragma unroll
        for (int j = 0; j < 4; ++j)
          acc[i][j] = __builtin_amdgcn_mfma_f32_16x16x32_bf16(af[i], bf[j], acc[i][j], 0, 0, 0);
    } else {
      // swapped: acc = C^T, rows n (d), cols m (nseq)
#pragma unroll
      for (int i = 0; i < 4; ++i)
#pragma unroll
        for (int j = 0; j < 4; ++j)
          acc[i][j] = __builtin_amdgcn_mfma_f32_16x16x32_bf16(bf[i], af[j], acc[i][j], 0, 0, 0);
    }
  }

  if (z == 2) {
#pragma unroll
    for (int i = 0; i < 4; ++i) {
#pragma unroll
      for (int j = 0; j < 4; ++j) {
        const int m0r = m0 + wy * 64 + i * 16 + quad * 4;  // key0 (4-aligned)
        const int n = n0 + wx * 64 + j * 16 + l15;         // inner dim
        const int b = m0r >> 12, nseq0 = m0r & 4095;
        const int h = n >> 6, d0 = n & 63;
        const int kti = nseq0 >> 5, kc = (nseq0 >> 4) & 1;
        // R17 pi-relayout: key k -> slot hiv=(k>>2)&1, eb=((k&15)>>3)*4+(k&3)
        const int hv = (nseq0 >> 2) & 1;
        const int e0 = ((nseq0 >> 3) & 1) * 4;             // e0 in {0,4}
        const int dt = (d0 >> 5) & 1, lv = hv * 32 + (d0 & 31);
        ushort4 u;
        u.x = f2bf(acc[i][j][0]); u.y = f2bf(acc[i][j][1]);
        u.z = f2bf(acc[i][j][2]); u.w = f2bf(acc[i][j][3]);
        *(ushort4*)(vtb + (size_t)(b * 8 + h) * 262144 +
                    ((((kti * 2 + dt) * 2 + kc) * 64 + lv) * 8 + e0)) = u;
      }
    }
  } else {
    const float qs = 0.18033688011112042f;  // 0.125*log2(e), z==0 only
#pragma unroll
    for (int i = 0; i < 4; ++i) {
#pragma unroll
      for (int j = 0; j < 4; ++j) {
        const int n0r = n0 + wx * 64 + i * 16 + quad * 4;  // inner dim, r=0
        const int m = m0 + wy * 64 + j * 16 + l15;         // nseq
        const int b = m >> 12, nseq = m & 4095;
        const int h = n0r >> 6, d0 = n0r & 63;
        ushort4 u;
        if (z == 0) {
          u.x = f2bf(acc[i][j][0] * qs); u.y = f2bf(acc[i][j][1] * qs);
          u.z = f2bf(acc[i][j][2] * qs); u.w = f2bf(acc[i][j][3] * qs);
          *(ushort4*)(qb + (size_t)((b * 8 + h) * 4096 + nseq) * 64 + d0) = u;
        } else {
          // K fragment-tiled: d0..d0+3 live in one 8-elem group (d0%4==0)
          const int kti = nseq >> 5, l31k = nseq & 31;
          const int c = (d0 >> 4) & 3, hk = (d0 >> 3) & 1, e0 = d0 & 7;
          u.x = f2bf(acc[i][j][0]); u.y = f2bf(acc[i][j][1]);
          u.z = f2bf(acc[i][j][2]); u.w = f2bf(acc[i][j][3]);
          *(ushort4*)(kb + (size_t)(b * 8 + h) * 262144 +
                      (((kti * 4 + c) * 64 + (hk * 32 + l31k)) * 8 + e0)) = u;
        }
      }
    }
  }
}

// ---------------- flash attention (32x32x16, register P, zero-shuffle) ---
// 256 thr = 4 waves = 2 key-groups x 2 waves; one (b,h); 128 Q rows/block,
// 64/wave (2 q-subtiles of 32). Group g handles keys [g*2048,(g+1)*2048).
// Grid 512 = 32 q-blocks x 16 bh (the R12-verified 87.9us configuration).
//
// S^T = mfma32(K, Q): lane (l31,hi) holds S[key=(r&3)+8*(r>>2)+4*hi][q=l31].
// exp2 -> f32; row-sums in VALU (half-key partials + one shfl_xor(32)); P
// packs via v_cvt_pk_bf16_f32 into wv[] -- and because V was written with
// the R17 k-permutation, pa[kc] = {wv[4kc+0..3]} DIRECTLY (A-side label
// pi(hi,e)=16kc+(e>>2)*8+4hi+(e&3) == B-side label by construction; the
// R12 exchange's 4 shfl + 12 selects per qs*kt are gone).
// s_setprio(1) wraps the MFMA clusters (T5: attn +4-7%, numerics-free).
//
// K/V loads: fragment-tiled layouts -> wave-contiguous lane-linear 1KB
// reads. No LDS, no barriers in main loop.
// bh XCD-swizzle: bh = 2*(L&7) + parity -> 2 bh = 2MB per XCD, L2-resident.
// Merge (additive, static max): R12-verbatim Ox + Lx[2][128]. 34816B LDS.

__global__ __launch_bounds__(256) void attn_k(
    const unsigned short* __restrict__ qb,   // [16][4096][64], pre-scaled
    const unsigned short* __restrict__ kb,   // [16][kti][c][lane][8] frag-tiled
    const unsigned short* __restrict__ vtb,  // [16][kti][dt][kc][lane][8] pi-perm
    unsigned short* __restrict__ ob) {       // [2][4096][512]
  __shared__ __align__(16) char smem[34816];  // epilogue merge only
  const int tid = threadIdx.x;
  const int w = tid >> 6, lane = tid & 63;
  const int l31 = lane & 31, hi = lane >> 5;
  const int g = w >> 1, wq = w & 1;  // key-group, wave-in-group

  const int L = blockIdx.x + 32 * blockIdx.y;        // 0..511
  const int bh = ((L & 7) << 1) | ((L >> 3) & 1);    // 2 bh per XCD
  const int q0 = (L >> 4) << 7;                      // 128-row q block

  const unsigned short* qbase = qb + (size_t)bh * (4096 * 64);
  const unsigned short* kbase = kb + (size_t)bh * 262144 + lane * 8;
  const unsigned short* vbase = vtb + (size_t)bh * 262144 + lane * 8;

  // Q fragments resident all kernel. B-frag: q=l31, d = c*16 + hi*8 + j.
  short8 qf[2][4];
#pragma unroll
  for (int qs = 0; qs < 2; ++qs) {
    const int qrow = q0 + wq * 64 + qs * 32 + l31;
#pragma unroll
    for (int c = 0; c < 4; ++c)
      qf[qs][c] = *(const short8*)(qbase + (size_t)qrow * 64 + c * 16 + hi * 8);
  }

  f32x16 Oacc[2][2];  // [qs][dt]; D-layout: q=(r&3)+8*(r>>2)+4*hi, d=l31+32dt
#pragma unroll
  for (int qs = 0; qs < 2; ++qs)
#pragma unroll
    for (int dt = 0; dt < 2; ++dt)
#pragma unroll
      for (int r = 0; r < 16; ++r) Oacc[qs][dt][r] = 0.f;
  float lsum[2] = {0.f, 0.f};  // per-lane: q=l31, keys of own hi-half

  const int jbase = g * 2048;

  for (int j0 = 0; j0 < 2048; j0 += 64) {
    const int kti0 = (jbase + j0) >> 5;
#pragma unroll
    for (int kt = 0; kt < 2; ++kt) {
      const int kti = kti0 + kt;
      short8 kf[4];
#pragma unroll
      for (int c = 0; c < 4; ++c)
        kf[c] = *(const short8*)(kbase + (size_t)(kti * 4 + c) * 512);
      short8 vf[2][2];
#pragma unroll
      for (int dt = 0; dt < 2; ++dt)
#pragma unroll
        for (int kc = 0; kc < 2; ++kc)
          vf[dt][kc] = *(const short8*)(vbase + (size_t)((kti * 2 + dt) * 2 + kc) * 512);

      uint4v pa[2][2];  // [qs][kc] PV A-frags (packed bf16 pairs)
#pragma unroll
      for (int qs = 0; qs < 2; ++qs) {
        f32x16 s;
#pragma unroll
        for (int r = 0; r < 16; ++r) s[r] = 0.f;
        __builtin_amdgcn_s_setprio(1);
#pragma unroll
        for (int c = 0; c < 4; ++c)
          s = __builtin_amdgcn_mfma_f32_32x32x16_bf16(kf[c], qf[qs][c], s, 0, 0, 0);
        __builtin_amdgcn_s_setprio(0);

        float e[16];
#pragma unroll
        for (int r = 0; r < 16; ++r) e[r] = fast_exp2(s[r]);
        lsum[qs] += (((e[0] + e[1]) + (e[2] + e[3])) + ((e[4] + e[5]) + (e[6] + e[7]))) +
                    (((e[8] + e[9]) + (e[10] + e[11])) + ((e[12] + e[13]) + (e[14] + e[15])));

        // pack key pairs: wv[g2*2+p] holds keys (8g2+4hi+2p, +1) for q=l31;
        // with the pi-permuted V this IS the A-frag order (zero-shuffle)
        unsigned int wv[8];
#pragma unroll
        for (int g2 = 0; g2 < 4; ++g2)
#pragma unroll
          for (int p = 0; p < 2; ++p)
            wv[g2 * 2 + p] = cvtpk_bf16(e[4 * g2 + 2 * p], e[4 * g2 + 2 * p + 1]);

        pa[qs][0] = (uint4v){wv[0], wv[1], wv[2], wv[3]};
        pa[qs][1] = (uint4v){wv[4], wv[5], wv[6], wv[7]};
      }

      // O += P V  (V-frags reused by both q-subtiles)
      __builtin_amdgcn_s_setprio(1);
#pragma unroll
      for (int dt = 0; dt < 2; ++dt)
#pragma unroll
        for (int kc = 0; kc < 2; ++kc)
#pragma unroll
          for (int qs = 0; qs < 2; ++qs)
            Oacc[qs][dt] = __builtin_amdgcn_mfma_f32_32x32x16_bf16(
                __builtin_bit_cast(short8, pa[qs][kc]), vf[dt][kc], Oacc[qs][dt], 0, 0, 0);
      __builtin_amdgcn_s_setprio(0);
    }
  }

  // per-q total L: combine complementary hi-halves (both halves end identical)
  float lt[2];
#pragma unroll
  for (int qs = 0; qs < 2; ++qs)
    lt[qs] = lsum[qs] + __shfl_xor(lsum[qs], 32, 64);

  // ----- merge the two key-groups (additive: static max; R12-verbatim) ---
  __syncthreads();                      // all compute done; smem usable
  float* Ox = (float*)smem;             // [128][66] fp32 (pad 2) = 33792 B
  float* Lx = (float*)(smem + 33792);   // [2][128] = 1024 B
#pragma unroll
  for (int qs = 0; qs < 2; ++qs)
    Lx[g * 128 + wq * 64 + qs * 32 + l31] = lt[qs];  // dup x2 benign
  if (g == 1) {
#pragma unroll
    for (int qs = 0; qs < 2; ++qs)
#pragma unroll
      for (int dt = 0; dt < 2; ++dt)
#pragma unroll
        for (int r = 0; r < 16; ++r) {
          const int row = wq * 64 + qs * 32 + (r & 3) + 8 * (r >> 2) + 4 * hi;
          Ox[row * 66 + dt * 32 + l31] = Oacc[qs][dt][r];
        }
  }
  __syncthreads();
  if (g == 0) {
    const int b = bh >> 3, h = bh & 7;
#pragma unroll
    for (int qs = 0; qs < 2; ++qs)
#pragma unroll
      for (int r = 0; r < 16; ++r) {
        const int row = wq * 64 + qs * 32 + (r & 3) + 8 * (r >> 2) + 4 * hi;
        const float inv = 1.0f / (Lx[row] + Lx[128 + row]);
#pragma unroll
        for (int dt = 0; dt < 2; ++dt)
          ob[(size_t)(b * 4096 + q0 + row) * 512 + h * 64 + dt * 32 + l31] =
              f2bf((Oacc[qs][dt][r] + Ox[row * 66 + dt * 32 + l31]) * inv);
      }
  }
}

// ---------------- output projection GEMM ----------------
// 128x64 tiles, SWAPPED mfma (C^T) so lane's 4 r-values are 4 consecutive
// out-cols at fixed row -> one float4 store (+ float4 bias load).

__global__ __launch_bounds__(256) void gemm_out_k(
    const unsigned short* __restrict__ A,    // o [8192][512]
    const unsigned short* __restrict__ Bt,   // WoT [768][512]
    const float* __restrict__ bias, float* __restrict__ out) {
  __shared__ __align__(16) short Al[4096];  // [128][32]
  __shared__ __align__(16) short Bl[2048];  // [64][32]
  const int tid = threadIdx.x;
  const int w = tid >> 6, lane = tid & 63, quad = lane >> 4, l15 = lane & 15;
  const int m0 = blockIdx.x * 128, n0 = blockIdx.y * 64;

  f32x4 acc[2][4];
#pragma unroll
  for (int i = 0; i < 2; ++i)
#pragma unroll
    for (int j = 0; j < 4; ++j) acc[i][j] = (f32x4){0.f, 0.f, 0.f, 0.f};

  for (int k0 = 0; k0 < 512; k0 += 32) {
    __syncthreads();
#pragma unroll
    for (int s = 0; s < 2; ++s) {
      const int t = s * 256 + tid;
      gld16(A + (size_t)(m0 + (t >> 2)) * 512 + k0 + (t & 3) * 8,
            Al + s * 2048 + w * 512);
    }
    gld16(Bt + (size_t)(n0 + (tid >> 2)) * 512 + k0 + (tid & 3) * 8,
          Bl + w * 512);
    __syncthreads();
    short8 af[2], bf[4];
#pragma unroll
    for (int i = 0; i < 2; ++i)
      af[i] = *(const short8*)(Al + (w * 32 + i * 16 + l15) * 32 + quad * 8);
#pragma unroll
    for (int j = 0; j < 4; ++j)
      bf[j] = *(const short8*)(Bl + (j * 16 + l15) * 32 + quad * 8);
    // swapped: acc[i][j] rows = out-col chunk j, cols = m chunk i
#pragma unroll
    for (int i = 0; i < 2; ++i)
#pragma unroll
      for (int j = 0; j < 4; ++j)
        acc[i][j] = __builtin_amdgcn_mfma_f32_16x16x32_bf16(bf[j], af[i], acc[i][j], 0, 0, 0);
  }

#pragma unroll
  for (int i = 0; i < 2; ++i) {
#pragma unroll
    for (int j = 0; j < 4; ++j) {
      const int col0 = n0 + j * 16 + quad * 4;
      const int m = m0 + w * 32 + i * 16 + l15;
      const float4 b4 = *(const float4*)(bias + col0);
      float4 o;
      o.x = acc[i][j][0] + b4.x; o.y = acc[i][j][1] + b4.y;
      o.z = acc[i][j][2] + b4.z; o.w = acc[i][j][3] + b4.w;
      *(float4*)(out + (size_t)m * 768 + col0) = o;
    }
  }
}

// ---------------- launch ----------------

extern "C" void kernel_launch(void* const* d_in, const int* in_sizes, int n_in,
                              void* d_out, int out_size, void* d_ws, size_t ws_size,
                              hipStream_t stream) {
  const float* x    = (const float*)d_in[0];
  const float* Wq   = (const float*)d_in[1];
  const float* Wk   = (const float*)d_in[2];
  const float* Wv   = (const float*)d_in[3];
  const float* Wout = (const float*)d_in[4];
  const float* bout = (const float*)d_in[5];
  float* out = (float*)d_out;
  char* ws = (char*)d_ws;

  // ws layout (bytes), total 49,283,072
  unsigned short* xb  = (unsigned short*)(ws);              // 12,582,912
  unsigned short* Wt  = (unsigned short*)(ws + 12582912);   //  2,359,296
  unsigned short* WoT = (unsigned short*)(ws + 14942208);   //    786,432
  unsigned short* qb  = (unsigned short*)(ws + 15728640);   //  8,388,608
  unsigned short* kb  = (unsigned short*)(ws + 24117248);   //  8,388,608
  unsigned short* vtb = (unsigned short*)(ws + 32505856);   //  8,388,608
  unsigned short* ob  = (unsigned short*)(ws + 40894464);   //  8,388,608

  cvt_x_k<<<6144, 256, 0, stream>>>(x, xb);
  transpose_w_k<<<dim3(24, 24, 4), 256, 0, stream>>>(Wq, Wk, Wv, Wout, Wt, WoT);
  gemm_qkv_k<<<dim3(64, 4, 3), 256, 0, stream>>>(xb, Wt, qb, kb, vtb);
  attn_k<<<dim3(32, 16), 256, 0, stream>>>(qb, kb, vtb, ob);
  gemm_out_k<<<dim3(64, 12), 256, 0, stream>>>(ob, WoT, bout, out);
}